// Round 3
// baseline (504.876 us; speedup 1.0000x reference)
//
#include <hip/hip_runtime.h>
#include <hip/hip_bf16.h>
#include <hip/hip_cooperative_groups.h>

namespace cg = cooperative_groups;

// Problem constants: B=64, C=256, H=W=56 -> HW=3136 (784 float4), SQ=64
#define SE_B     64
#define SE_C     256
#define SE_SQ    64
#define SE_HW    3136
#define SE_HW4   784
#define SE_PLANES (SE_B * SE_C)   // 16384

#define NBLK  512                  // 2 blocks/CU guaranteed co-resident
#define NWAVE (NBLK * 4)           // 2048 waves -> 8 planes/wave

// ---------------------------------------------------------------------------
// Single persistent cooperative kernel:
//   phase 1: pool   (one wave per plane, grid-stride) -> s[16384]
//   phase 2: fc     (blocks 0..63, one per batch)     -> g[16384]
//   phase 3: scale  (same plane mapping; x re-read should hit L3)
// launch_bounds(256,2): VGPR cap 256 — no spill risk, co-residency safe.
// ---------------------------------------------------------------------------
__global__ __launch_bounds__(256, 2) void se_fused(
        const float* __restrict__ x,
        const float* __restrict__ w1, const float* __restrict__ b1,
        const float* __restrict__ w2, const float* __restrict__ b2,
        float* __restrict__ s, float* __restrict__ g,
        float* __restrict__ out) {
    cg::grid_group grid = cg::this_grid();
    const int wave = threadIdx.x >> 6;
    const int lane = threadIdx.x & 63;
    const int wid  = blockIdx.x * 4 + wave;        // 0..NWAVE-1

    // ---- phase 1: global average pool --------------------------------------
    for (int plane = wid; plane < SE_PLANES; plane += NWAVE) {
        const float4* xp = (const float4*)(x + (size_t)plane * SE_HW);
        float sum = 0.0f;
        #pragma unroll
        for (int it = 0; it < 12; ++it) {
            float4 v = xp[lane + it * 64];
            sum += (v.x + v.y) + (v.z + v.w);
        }
        if (lane < 16) {                            // 784 = 12*64 + 16
            float4 v = xp[lane + 768];
            sum += (v.x + v.y) + (v.z + v.w);
        }
        #pragma unroll
        for (int off = 32; off > 0; off >>= 1)
            sum += __shfl_down(sum, off, 64);
        if (lane == 0) s[plane] = sum * (1.0f / (float)SE_HW);
    }
    grid.sync();

    // ---- phase 2: excitation MLP (64 active blocks) ------------------------
    __shared__ float s_sh[SE_C];
    __shared__ float h_sh[SE_SQ];
    if (blockIdx.x < SE_B) {
        const int b = blockIdx.x;
        s_sh[threadIdx.x] = s[b * SE_C + threadIdx.x];
        __syncthreads();
        if (threadIdx.x < SE_SQ) {
            float acc = b1[threadIdx.x];
            const float4* w  = (const float4*)(w1 + (size_t)threadIdx.x * SE_C);
            const float4* ss = (const float4*)s_sh;
            #pragma unroll 8
            for (int c = 0; c < SE_C / 4; ++c) {
                float4 wv = w[c], sv = ss[c];
                acc = fmaf(wv.x, sv.x, acc);
                acc = fmaf(wv.y, sv.y, acc);
                acc = fmaf(wv.z, sv.z, acc);
                acc = fmaf(wv.w, sv.w, acc);
            }
            h_sh[threadIdx.x] = fmaxf(acc, 0.0f);
        }
        __syncthreads();
        float acc = b2[threadIdx.x];
        const float4* w  = (const float4*)(w2 + (size_t)threadIdx.x * SE_SQ);
        const float4* hh = (const float4*)h_sh;
        #pragma unroll
        for (int k = 0; k < SE_SQ / 4; ++k) {
            float4 wv = w[k], hv = hh[k];
            acc = fmaf(wv.x, hv.x, acc);
            acc = fmaf(wv.y, hv.y, acc);
            acc = fmaf(wv.z, hv.z, acc);
            acc = fmaf(wv.w, hv.w, acc);
        }
        g[b * SE_C + threadIdx.x] = 1.0f / (1.0f + __expf(-acc));
    }
    grid.sync();

    // ---- phase 3: broadcast scale (x re-read — L3 resident) ----------------
    for (int plane = wid; plane < SE_PLANES; plane += NWAVE) {
        const float gv = g[plane];
        const float4* xp = (const float4*)(x + (size_t)plane * SE_HW);
        float4* op = (float4*)(out + (size_t)plane * SE_HW);
        #pragma unroll
        for (int it = 0; it < 12; ++it) {
            float4 v = xp[lane + it * 64];
            v.x *= gv; v.y *= gv; v.z *= gv; v.w *= gv;
            op[lane + it * 64] = v;
        }
        if (lane < 16) {
            float4 v = xp[lane + 768];
            v.x *= gv; v.y *= gv; v.z *= gv; v.w *= gv;
            op[lane + 768] = v;
        }
    }
}

extern "C" void kernel_launch(void* const* d_in, const int* in_sizes, int n_in,
                              void* d_out, int out_size, void* d_ws, size_t ws_size,
                              hipStream_t stream) {
    const float* x  = (const float*)d_in[0];
    const float* w1 = (const float*)d_in[1];
    const float* b1 = (const float*)d_in[2];
    const float* w2 = (const float*)d_in[3];
    const float* b2 = (const float*)d_in[4];
    float* out = (float*)d_out;

    // workspace: s[16384] then g[16384] — fully overwritten before read
    float* s = (float*)d_ws;
    float* g = s + SE_PLANES;

    void* args[] = {(void*)&x, (void*)&w1, (void*)&b1, (void*)&w2, (void*)&b2,
                    (void*)&s, (void*)&g, (void*)&out};
    hipLaunchCooperativeKernel((const void*)se_fused, dim3(NBLK), dim3(256),
                               args, 0, stream);
}